// Round 1
// baseline (1849.490 us; speedup 1.0000x reference)
//
#include <hip/hip_runtime.h>
#include <math.h>

#define NN 50000
#define EE 800000
#define GG 2000
#define HH 128
#define FN 64
#define FE 16

// ---------------- device helpers ----------------
__device__ __forceinline__ float leakyf(float v){ return v>=0.f ? v : 0.01f*v; }
__device__ __forceinline__ float eluf(float v){ return v>0.f ? v : expm1f(v); }
__device__ __forceinline__ float sigmf(float v){ return 1.f/(1.f+__expf(-v)); }

__device__ __forceinline__ float wsum(float v){
#pragma unroll
  for(int m=32;m>=1;m>>=1) v += __shfl_xor(v,m,64);
  return v;
}
__device__ __forceinline__ float wmax64(float v){
#pragma unroll
  for(int m=32;m>=1;m>>=1) v = fmaxf(v,__shfl_xor(v,m,64));
  return v;
}

// ---------------- CSR build ----------------
__global__ void k_count_edges(const int* __restrict__ dst, int* __restrict__ deg){
  int e = blockIdx.x*256 + threadIdx.x;
  if(e < EE) atomicAdd(&deg[dst[e]], 1);
}

__global__ void k_count_graphs(const int* __restrict__ batch, int* __restrict__ gcnt){
  int n = blockIdx.x*256 + threadIdx.x;
  if(n < NN) atomicAdd(&gcnt[batch[n]], 1);
}

// single-block exclusive scan: off[0]=0, off[i+1]=sum(cnt[0..i])
__global__ void k_scan(const int* __restrict__ cnt, int* __restrict__ off, int n){
  __shared__ int part[1024];
  int t = threadIdx.x;
  int C = (n + 1023) >> 10;
  int lo = t*C, hi = min(lo + C, n);
  int s = 0;
  for(int i=lo;i<hi;i++) s += cnt[i];
  part[t] = s;
  __syncthreads();
  for(int o=1;o<1024;o<<=1){
    int v = (t>=o) ? part[t-o] : 0;
    __syncthreads();
    part[t] += v;
    __syncthreads();
  }
  int base = part[t] - s;   // exclusive prefix for this chunk
  int run = base;
  for(int i=lo;i<hi;i++){ run += cnt[i]; off[i+1] = run; }
  if(t==0) off[0] = 0;
}

__global__ void k_scatter_edges(const int* __restrict__ src, const int* __restrict__ dst,
                                const int* __restrict__ eoff, int* __restrict__ cur,
                                int* __restrict__ esrc_s, int* __restrict__ eperm){
  int e = blockIdx.x*256 + threadIdx.x;
  if(e < EE){
    int d = dst[e];
    int pos = eoff[d] + atomicAdd(&cur[d], 1);
    esrc_s[pos] = src[e];
    eperm[e] = pos;
  }
}

// ---------------- generic GEMM: C[M,128] = act(A[M,K] @ W[128,K]^T (+bias)) ----------------
// ACT: 0 = none, 1 = leaky + bias
template<int ACT>
__global__ __launch_bounds__(256) void k_gemm128(const float* __restrict__ A,
                                                 const float* __restrict__ W,
                                                 const float* __restrict__ bias,
                                                 float* __restrict__ C, int M, int K){
  __shared__ float As[16][68];
  __shared__ float Bs[16][68];
  const int tid = threadIdx.x;
  const int tx = tid & 15, ty = tid >> 4;
  const int m0 = blockIdx.x * 64, c0 = blockIdx.y * 64;
  float acc[4][4] = {};
  const int lm = tid >> 2, lk = (tid & 3) * 4;

  for(int k0=0;k0<K;k0+=16){
    float4 av = make_float4(0.f,0.f,0.f,0.f);
    if(m0 + lm < M) av = *(const float4*)&A[(size_t)(m0+lm)*K + k0 + lk];
    As[lk+0][lm]=av.x; As[lk+1][lm]=av.y; As[lk+2][lm]=av.z; As[lk+3][lm]=av.w;
    float4 bv = *(const float4*)&W[(size_t)(c0+lm)*K + k0 + lk];
    Bs[lk+0][lm]=bv.x; Bs[lk+1][lm]=bv.y; Bs[lk+2][lm]=bv.z; Bs[lk+3][lm]=bv.w;
    __syncthreads();
#pragma unroll
    for(int k=0;k<16;k++){
      float4 a = *(const float4*)&As[k][ty*4];
      float4 b = *(const float4*)&Bs[k][tx*4];
      float aa[4] = {a.x,a.y,a.z,a.w};
      float bb[4] = {b.x,b.y,b.z,b.w};
#pragma unroll
      for(int i=0;i<4;i++)
#pragma unroll
        for(int j=0;j<4;j++) acc[i][j] += aa[i]*bb[j];
    }
    __syncthreads();
  }
#pragma unroll
  for(int i=0;i<4;i++){
    int r = m0 + ty*4 + i;
    if(r < M){
      float4 o;
      float v0=acc[i][0], v1=acc[i][1], v2=acc[i][2], v3=acc[i][3];
      int c = c0 + tx*4;
      if(ACT==1){
        v0 = leakyf(v0 + bias[c+0]); v1 = leakyf(v1 + bias[c+1]);
        v2 = leakyf(v2 + bias[c+2]); v3 = leakyf(v3 + bias[c+3]);
      }
      o.x=v0;o.y=v1;o.z=v2;o.w=v3;
      *(float4*)&C[(size_t)r*HH + c] = o;
    }
  }
}

// ---------------- GATEConv edge-alpha GEMM ----------------
// per edge e: hj = leaky([x[src]|ea] @ W1^T); s = sum_c leaky(hj_c)*attl_c;
// alpha_sorted[eperm[e]] = leaky(s + RD[dst[e]])
__global__ __launch_bounds__(256) void k_gate_alpha(const float* __restrict__ X,
                                                    const float* __restrict__ EA,
                                                    const int* __restrict__ esrc0,
                                                    const int* __restrict__ edst0,
                                                    const float* __restrict__ W1,
                                                    const float* __restrict__ attl,
                                                    const float* __restrict__ RD,
                                                    const int* __restrict__ eperm,
                                                    float* __restrict__ ALPHA){
  __shared__ float As[16][68];
  __shared__ float Bs[16][132];
  __shared__ int SRC[64];
  const int tid = threadIdx.x;
  const int tx = tid & 15, ty = tid >> 4;   // ty 0..15: rows ty*4..; tx: cols tx*8..
  const int e0 = blockIdx.x * 64;
  if(tid < 64) SRC[tid] = esrc0[e0 + tid];
  __syncthreads();

  float acc[4][8] = {};
  const int lm = tid >> 2, lk = (tid & 3) * 4;

#pragma unroll 1
  for(int step=0;step<9;step++){
    const int k0 = step*16;
    float4 av;
    if(step < 8) av = *(const float4*)&X[(size_t)SRC[lm]*HH + k0 + lk];
    else         av = *(const float4*)&EA[(size_t)(e0+lm)*FE + lk];
    As[lk+0][lm]=av.x; As[lk+1][lm]=av.y; As[lk+2][lm]=av.z; As[lk+3][lm]=av.w;
#pragma unroll
    for(int q=0;q<2;q++){
      int idx = tid + q*256;          // 0..511
      int c = idx >> 2;               // 0..127
      int kq = (idx & 3) * 4;
      float4 bv = *(const float4*)&W1[(size_t)c*144 + k0 + kq];
      Bs[kq+0][c]=bv.x; Bs[kq+1][c]=bv.y; Bs[kq+2][c]=bv.z; Bs[kq+3][c]=bv.w;
    }
    __syncthreads();
#pragma unroll
    for(int k=0;k<16;k++){
      float4 a = *(const float4*)&As[k][ty*4];
      float aa[4]={a.x,a.y,a.z,a.w};
      float4 b0 = *(const float4*)&Bs[k][tx*8];
      float4 b1 = *(const float4*)&Bs[k][tx*8+4];
      float bb[8]={b0.x,b0.y,b0.z,b0.w,b1.x,b1.y,b1.z,b1.w};
#pragma unroll
      for(int i=0;i<4;i++)
#pragma unroll
        for(int j=0;j<8;j++) acc[i][j] += aa[i]*bb[j];
    }
    __syncthreads();
  }

  float al[8];
#pragma unroll
  for(int j=0;j<8;j++) al[j] = attl[tx*8+j];
#pragma unroll
  for(int i=0;i<4;i++){
    float p = 0.f;
#pragma unroll
    for(int j=0;j<8;j++) p += leakyf(acc[i][j]) * al[j];
#pragma unroll
    for(int m=1;m<16;m<<=1) p += __shfl_xor(p,m,64);
    if(tx==0){
      int e = e0 + ty*4 + i;
      float a = leakyf(p + RD[edst0[e]]);
      ALPHA[eperm[e]] = a;
    }
  }
}

// ---------------- segment softmax + weighted aggregation (wave per segment) ----------------
// MODE 0: GATE (alpha precomputed & sorted), items = esrc_sorted, nseg=N
// MODE 1: ATOM (alpha = leaky(A1[items[i]] + A2[seg])), items = esrc_sorted, nseg=N
// MODE 2: MOL  (alpha = leaky(A1[i] + A2[seg])), item = i (contiguous nodes), nseg=G
template<int MODE>
__global__ void k_agg(const int* __restrict__ off, const int* __restrict__ items,
                      const float* __restrict__ ALPHA, const float* __restrict__ A1,
                      const float* __restrict__ A2, const float* __restrict__ XSrc,
                      const float* __restrict__ bias, float* __restrict__ OUT, int nseg){
  int w = (blockIdx.x*blockDim.x + threadIdx.x) >> 6;
  int lane = threadIdx.x & 63;
  if(w >= nseg) return;
  int s0 = off[w], s1 = off[w+1];
  float a2 = (MODE==0) ? 0.f : A2[w];

  float m = -INFINITY;
  for(int i=s0+lane;i<s1;i+=64){
    float a;
    if(MODE==0) a = ALPHA[i];
    else if(MODE==1) a = leakyf(A1[items[i]] + a2);
    else a = leakyf(A1[i] + a2);
    m = fmaxf(m, a);
  }
  m = wmax64(m);

  float s = 0.f;
  for(int i=s0+lane;i<s1;i+=64){
    float a;
    if(MODE==0) a = ALPHA[i];
    else if(MODE==1) a = leakyf(A1[items[i]] + a2);
    else a = leakyf(A1[i] + a2);
    s += __expf(a - m);
  }
  s = wsum(s);
  float inv = 1.f/(s + 1e-16f);

  float h0=0.f, h1=0.f;
  for(int i=s0;i<s1;i++){
    int it = (MODE==2) ? i : items[i];
    float a;
    if(MODE==0) a = ALPHA[i];
    else a = leakyf(A1[it] + a2);
    float wg = __expf(a - m);
    h0 += wg * XSrc[(size_t)it*HH + lane];
    h1 += wg * XSrc[(size_t)it*HH + 64 + lane];
  }
  h0 = h0*inv + bias[lane];
  h1 = h1*inv + bias[64+lane];
  OUT[(size_t)w*HH + lane]      = eluf(h0);
  OUT[(size_t)w*HH + 64 + lane] = eluf(h1);
}

// ---------------- fused GRUCell: XOUT = relu(GRU(MSG, X)) ----------------
__global__ __launch_bounds__(256) void k_gru(const float* __restrict__ MSG,
                                             const float* __restrict__ X,
                                             const float* __restrict__ Wih,
                                             const float* __restrict__ Whh,
                                             const float* __restrict__ bih,
                                             const float* __restrict__ bhh,
                                             float* __restrict__ XOUT, int M){
  __shared__ float As[2][16][68];
  __shared__ float Bs[6][16][68];
  const int tid = threadIdx.x;
  const int tx = tid & 15, ty = tid >> 4;
  const int m0 = blockIdx.x * 64, c0 = blockIdx.y * 64;
  float acc[6][4][4] = {};
  const int lm = tid >> 2, lk = (tid & 3) * 4;

  for(int k0=0;k0<HH;k0+=16){
    float4 a0 = make_float4(0,0,0,0), a1 = make_float4(0,0,0,0);
    if(m0+lm < M){
      a0 = *(const float4*)&MSG[(size_t)(m0+lm)*HH + k0 + lk];
      a1 = *(const float4*)&X  [(size_t)(m0+lm)*HH + k0 + lk];
    }
    As[0][lk+0][lm]=a0.x; As[0][lk+1][lm]=a0.y; As[0][lk+2][lm]=a0.z; As[0][lk+3][lm]=a0.w;
    As[1][lk+0][lm]=a1.x; As[1][lk+1][lm]=a1.y; As[1][lk+2][lm]=a1.z; As[1][lk+3][lm]=a1.w;
#pragma unroll
    for(int pl=0;pl<6;pl++){
      const float* Wp = (pl<3) ? Wih : Whh;
      int row = (pl%3)*HH + c0 + lm;
      float4 bv = *(const float4*)&Wp[(size_t)row*HH + k0 + lk];
      Bs[pl][lk+0][lm]=bv.x; Bs[pl][lk+1][lm]=bv.y; Bs[pl][lk+2][lm]=bv.z; Bs[pl][lk+3][lm]=bv.w;
    }
    __syncthreads();
#pragma unroll
    for(int k=0;k<16;k++){
      float4 am = *(const float4*)&As[0][k][ty*4];
      float4 ax = *(const float4*)&As[1][k][ty*4];
      float amm[4]={am.x,am.y,am.z,am.w};
      float axx[4]={ax.x,ax.y,ax.z,ax.w};
      float bb[6][4];
#pragma unroll
      for(int pl=0;pl<6;pl++){
        float4 b = *(const float4*)&Bs[pl][k][tx*4];
        bb[pl][0]=b.x; bb[pl][1]=b.y; bb[pl][2]=b.z; bb[pl][3]=b.w;
      }
#pragma unroll
      for(int i=0;i<4;i++)
#pragma unroll
        for(int j=0;j<4;j++){
          acc[0][i][j] += amm[i]*bb[0][j];
          acc[1][i][j] += amm[i]*bb[1][j];
          acc[2][i][j] += amm[i]*bb[2][j];
          acc[3][i][j] += axx[i]*bb[3][j];
          acc[4][i][j] += axx[i]*bb[4][j];
          acc[5][i][j] += axx[i]*bb[5][j];
        }
    }
    __syncthreads();
  }

  float bi0[4], bi1[4], bi2[4], bh0[4], bh1[4], bh2[4];
#pragma unroll
  for(int j=0;j<4;j++){
    int c = c0 + tx*4 + j;
    bi0[j]=bih[c]; bi1[j]=bih[c+HH]; bi2[j]=bih[c+2*HH];
    bh0[j]=bhh[c]; bh1[j]=bhh[c+HH]; bh2[j]=bhh[c+2*HH];
  }
#pragma unroll
  for(int i=0;i<4;i++){
    int r = m0 + ty*4 + i;
    if(r < M){
      float4 hp = *(const float4*)&X[(size_t)r*HH + c0 + tx*4];
      float hpv[4]={hp.x,hp.y,hp.z,hp.w};
      float ov[4];
#pragma unroll
      for(int j=0;j<4;j++){
        float ir = acc[0][i][j]+bi0[j], iz = acc[1][i][j]+bi1[j], inn = acc[2][i][j]+bi2[j];
        float hr = acc[3][i][j]+bh0[j], hz = acc[4][i][j]+bh1[j], hn  = acc[5][i][j]+bh2[j];
        float rr = sigmf(ir+hr);
        float z  = sigmf(iz+hz);
        float ng = tanhf(inn + rr*hn);
        float nx = (1.f - z)*ng + z*hpv[j];
        ov[j] = fmaxf(nx, 0.f);
      }
      float4 o; o.x=ov[0]; o.y=ov[1]; o.z=ov[2]; o.w=ov[3];
      *(float4*)&XOUT[(size_t)r*HH + c0 + tx*4] = o;
    }
  }
}

// ---------------- small per-row kernels ----------------
// wave per row: a[r] = X[r]·u  (and b[r] = X[r]·v if v != null)
__global__ void k_dot2(const float* __restrict__ X, const float* __restrict__ u,
                       const float* __restrict__ v, float* __restrict__ a,
                       float* __restrict__ b, int M){
  int w = (blockIdx.x*blockDim.x + threadIdx.x) >> 6;
  int lane = threadIdx.x & 63;
  if(w >= M) return;
  float x0 = X[(size_t)w*HH + lane];
  float x1 = X[(size_t)w*HH + 64 + lane];
  float p = x0*u[lane] + x1*u[64+lane];
  p = wsum(p);
  if(lane==0) a[w] = p;
  if(v){
    float q = x0*v[lane] + x1*v[64+lane];
    q = wsum(q);
    if(lane==0) b[w] = q;
  }
}

// wave per graph: OUT[g] = relu(sum of X rows in [goff[g],goff[g+1]))
__global__ void k_ginit(const int* __restrict__ goff, const float* __restrict__ X,
                        float* __restrict__ OUT){
  int g = (blockIdx.x*blockDim.x + threadIdx.x) >> 6;
  int lane = threadIdx.x & 63;
  if(g >= GG) return;
  int s0 = goff[g], s1 = goff[g+1];
  float h0=0.f, h1=0.f;
  for(int n=s0;n<s1;n++){
    h0 += X[(size_t)n*HH + lane];
    h1 += X[(size_t)n*HH + 64 + lane];
  }
  OUT[(size_t)g*HH + lane]      = fmaxf(h0, 0.f);
  OUT[(size_t)g*HH + 64 + lane] = fmaxf(h1, 0.f);
}

// weff[c] = sum_j finW[j]*lin2W[j][c]; weff[128] = sum_j lin2b[j]*finW[j] + finb
__global__ void k_weff(const float* __restrict__ lin2W, const float* __restrict__ lin2b,
                       const float* __restrict__ finW, const float* __restrict__ finb,
                       float* __restrict__ weff){
  int c = threadIdx.x;
  float s = 0.f;
  for(int j=0;j<HH;j++) s += finW[j]*lin2W[(size_t)j*HH + c];
  weff[c] = s;
  if(c==0){
    float bb = finb[0];
    for(int j=0;j<HH;j++) bb += lin2b[j]*finW[j];
    weff[HH] = bb;
  }
}

// y[g] = sigmoid(OUT[g]·weff + weff[128])
__global__ void k_final(const float* __restrict__ OUT, const float* __restrict__ weff,
                        float* __restrict__ y){
  int g = (blockIdx.x*blockDim.x + threadIdx.x) >> 6;
  int lane = threadIdx.x & 63;
  if(g >= GG) return;
  float p = OUT[(size_t)g*HH + lane]*weff[lane] + OUT[(size_t)g*HH + 64 + lane]*weff[64+lane];
  p = wsum(p);
  if(lane==0) y[g] = sigmf(p + weff[HH]);
}

// ---------------- host ----------------
extern "C" void kernel_launch(void* const* d_in, const int* in_sizes, int n_in,
                              void* d_out, int out_size, void* d_ws, size_t ws_size,
                              hipStream_t stream){
  const float* in_x   = (const float*)d_in[0];
  const int*   eidx   = (const int*)d_in[1];
  const float* ea     = (const float*)d_in[2];
  const int*   batch  = (const int*)d_in[3];
  const float* lin1W  = (const float*)d_in[4];
  const float* lin1b  = (const float*)d_in[5];
  const float* gattl  = (const float*)d_in[6];
  const float* gattr  = (const float*)d_in[7];
  const float* glin1W = (const float*)d_in[8];
  const float* glin2W = (const float*)d_in[9];
  const float* gbias  = (const float*)d_in[10];
  const float* g0Wih  = (const float*)d_in[11];
  const float* g0Whh  = (const float*)d_in[12];
  const float* g0bih  = (const float*)d_in[13];
  const float* g0bhh  = (const float*)d_in[14];
  const float* aLinW  = (const float*)d_in[15];
  const float* aAttS  = (const float*)d_in[16];
  const float* aAttD  = (const float*)d_in[17];
  const float* aBias  = (const float*)d_in[18];
  const float* aGWih  = (const float*)d_in[19];
  const float* aGWhh  = (const float*)d_in[20];
  const float* aGbih  = (const float*)d_in[21];
  const float* aGbhh  = (const float*)d_in[22];
  const float* mLinW  = (const float*)d_in[23];
  const float* mAttS  = (const float*)d_in[24];
  const float* mAttD  = (const float*)d_in[25];
  const float* mBias  = (const float*)d_in[26];
  const float* mGWih  = (const float*)d_in[27];
  const float* mGWhh  = (const float*)d_in[28];
  const float* mGbih  = (const float*)d_in[29];
  const float* mGbhh  = (const float*)d_in[30];
  const float* lin2W  = (const float*)d_in[31];
  const float* lin2b  = (const float*)d_in[32];
  const float* finW   = (const float*)d_in[33];
  const float* finb   = (const float*)d_in[34];

  const int* esrc0 = eidx;        // edge_index[0] = source
  const int* edst0 = eidx + EE;   // edge_index[1] = target

  // workspace carve-up
  char* w = (char*)d_ws;
  size_t o = 0;
  auto alloc = [&](size_t bytes)->void*{
    void* p = w + o;
    o = (o + bytes + 255) & ~(size_t)255;
    return p;
  };
  float* X    = (float*)alloc((size_t)NN*HH*4);
  float* XB   = (float*)alloc((size_t)NN*HH*4);
  float* XS   = (float*)alloc((size_t)NN*HH*4);
  float* MSG  = (float*)alloc((size_t)NN*HH*4);
  float* ALPHA= (float*)alloc((size_t)EE*4);
  float* S1   = (float*)alloc((size_t)NN*4);
  float* S2   = (float*)alloc((size_t)NN*4);
  float* ADSTG= (float*)alloc((size_t)GG*4);
  float* OUTg = (float*)alloc((size_t)GG*HH*4);
  float* OUTb = (float*)alloc((size_t)GG*HH*4);
  float* HG   = (float*)alloc((size_t)GG*HH*4);
  float* ODg  = (float*)alloc((size_t)GG*HH*4);
  float* WEFF = (float*)alloc(256*4);
  int* zeroreg= (int*)alloc((size_t)(NN + NN + 2048)*4); // deg | cur | gcnt
  int* deg  = zeroreg;
  int* cur  = zeroreg + NN;
  int* gcnt = zeroreg + 2*NN;
  int* eoff = (int*)alloc((size_t)(NN+1)*4);
  int* goff = (int*)alloc((size_t)(GG+1)*4);
  int* esrcS= (int*)alloc((size_t)EE*4);
  int* eperm= (int*)alloc((size_t)EE*4);

  // ---- CSR build ----
  hipMemsetAsync(zeroreg, 0, (size_t)(NN + NN + 2048)*4, stream);
  k_count_edges<<<EE/256, 256, 0, stream>>>(edst0, deg);
  k_scan<<<1, 1024, 0, stream>>>(deg, eoff, NN);
  k_scatter_edges<<<EE/256, 256, 0, stream>>>(esrc0, edst0, eoff, cur, esrcS, eperm);
  k_count_graphs<<<(NN+255)/256, 256, 0, stream>>>(batch, gcnt);
  k_scan<<<1, 1024, 0, stream>>>(gcnt, goff, GG);

  const int gN  = (NN + 63)/64;     // GEMM row blocks for N
  const int gG  = (GG + 63)/64;
  dim3 gemmN(gN, 2), gemmG(gG, 2);

  // ---- input projection: X = leaky(x @ lin1W^T + lin1b) ----
  k_gemm128<1><<<gemmN, 256, 0, stream>>>(in_x, lin1W, lin1b, X, NN, FN);

  // ---- GATEConv ----
  k_dot2<<<(NN+3)/4, 256, 0, stream>>>(X, gattr, nullptr, S1, nullptr, NN);  // S1 = r per node
  k_gemm128<0><<<gemmN, 256, 0, stream>>>(X, glin2W, nullptr, XS, NN, HH);
  k_gate_alpha<<<EE/64, 256, 0, stream>>>(X, ea, esrc0, edst0, glin1W, gattl, S1, eperm, ALPHA);
  k_agg<0><<<(NN+3)/4, 256, 0, stream>>>(eoff, esrcS, ALPHA, nullptr, nullptr, XS, gbias, MSG, NN);
  k_gru<<<gemmN, 256, 0, stream>>>(MSG, X, g0Wih, g0Whh, g0bih, g0bhh, XB, NN);
  { float* t = X; X = XB; XB = t; }

  // ---- atom GATConv layers ----
  for(int l=0;l<2;l++){
    const float* Wl   = aLinW + (size_t)l*HH*HH;
    const float* asl  = aAttS + (size_t)l*HH;
    const float* adl  = aAttD + (size_t)l*HH;
    const float* bl   = aBias + (size_t)l*HH;
    const float* wih  = aGWih + (size_t)l*3*HH*HH;
    const float* whh  = aGWhh + (size_t)l*3*HH*HH;
    const float* bi   = aGbih + (size_t)l*3*HH;
    const float* bh   = aGbhh + (size_t)l*3*HH;
    k_gemm128<0><<<gemmN, 256, 0, stream>>>(X, Wl, nullptr, XS, NN, HH);
    k_dot2<<<(NN+3)/4, 256, 0, stream>>>(XS, asl, adl, S1, S2, NN);
    k_agg<1><<<(NN+3)/4, 256, 0, stream>>>(eoff, esrcS, nullptr, S1, S2, XS, bl, MSG, NN);
    k_gru<<<gemmN, 256, 0, stream>>>(MSG, X, wih, whh, bi, bh, XB, NN);
    { float* t = X; X = XB; XB = t; }
  }

  // ---- molecule readout ----
  k_ginit<<<(GG+3)/4, 256, 0, stream>>>(goff, X, OUTg);
  k_gemm128<0><<<gemmN, 256, 0, stream>>>(X, mLinW, nullptr, XS, NN, HH);   // xs (fixed)
  k_dot2<<<(NN+3)/4, 256, 0, stream>>>(XS, mAttS, nullptr, S1, nullptr, NN); // a_src

  float* Ocur = OUTg;
  float* Onxt = OUTb;
  for(int t=0;t<3;t++){
    k_gemm128<0><<<gemmG, 256, 0, stream>>>(Ocur, mLinW, nullptr, ODg, GG, HH);
    k_dot2<<<(GG+3)/4, 256, 0, stream>>>(ODg, mAttD, nullptr, ADSTG, nullptr, GG);
    k_agg<2><<<(GG+3)/4, 256, 0, stream>>>(goff, nullptr, nullptr, S1, ADSTG, XS, mBias, HG, GG);
    k_gru<<<gemmG, 256, 0, stream>>>(HG, Ocur, mGWih, mGWhh, mGbih, mGbhh, Onxt, GG);
    { float* tt = Ocur; Ocur = Onxt; Onxt = tt; }
  }

  // ---- fused lin2 + final ----
  k_weff<<<1, 128, 0, stream>>>(lin2W, lin2b, finW, finb, WEFF);
  k_final<<<(GG+3)/4, 256, 0, stream>>>(Ocur, WEFF, (float*)d_out);
}

// Round 3
// 1639.653 us; speedup vs baseline: 1.1280x; 1.1280x over previous
//
#include <hip/hip_runtime.h>
#include <math.h>

#define NN 50000
#define EE 800000
#define GG 2000
#define HH 128
#define FN 64
#define FE 16

// ---------------- device helpers ----------------
__device__ __forceinline__ float leakyf(float v){ return v>=0.f ? v : 0.01f*v; }
__device__ __forceinline__ float eluf(float v){ return v>0.f ? v : expm1f(v); }
__device__ __forceinline__ float sigmf(float v){ return 1.f/(1.f+__expf(-v)); }
__device__ __forceinline__ float tanh_fast(float x){
  float ax = fabsf(x);
  float e = __expf(-2.f*ax);
  float t = (1.f - e)/(1.f + e);
  return x>=0.f ? t : -t;
}
// uniform-index cross-lane broadcast via readlane (SGPR, frees LDS pipe)
__device__ __forceinline__ int rdl(int v, int l){ return __builtin_amdgcn_readlane(v, l); }
__device__ __forceinline__ float rdlf(float v, int l){
  return __int_as_float(__builtin_amdgcn_readlane(__float_as_int(v), l));
}

__device__ __forceinline__ float wsum(float v){
#pragma unroll
  for(int m=32;m>=1;m>>=1) v += __shfl_xor(v,m,64);
  return v;
}
__device__ __forceinline__ float wmax64(float v){
#pragma unroll
  for(int m=32;m>=1;m>>=1) v = fmaxf(v,__shfl_xor(v,m,64));
  return v;
}

// ---------------- CSR build ----------------
__global__ void k_count_edges(const int* __restrict__ dst, int* __restrict__ deg){
  int e = blockIdx.x*256 + threadIdx.x;
  if(e < EE) atomicAdd(&deg[dst[e]], 1);
}

__global__ void k_count_graphs(const int* __restrict__ batch, int* __restrict__ gcnt){
  int n = blockIdx.x*256 + threadIdx.x;
  if(n < NN) atomicAdd(&gcnt[batch[n]], 1);
}

__global__ void k_scan(const int* __restrict__ cnt, int* __restrict__ off, int n){
  __shared__ int part[1024];
  int t = threadIdx.x;
  int C = (n + 1023) >> 10;
  int lo = t*C, hi = min(lo + C, n);
  int s = 0;
  for(int i=lo;i<hi;i++) s += cnt[i];
  part[t] = s;
  __syncthreads();
  for(int o=1;o<1024;o<<=1){
    int v = (t>=o) ? part[t-o] : 0;
    __syncthreads();
    part[t] += v;
    __syncthreads();
  }
  int base = part[t] - s;
  int run = base;
  for(int i=lo;i<hi;i++){ run += cnt[i]; off[i+1] = run; }
  if(t==0) off[0] = 0;
}

__global__ void k_scatter_edges(const int* __restrict__ src, const int* __restrict__ dst,
                                const int* __restrict__ eoff, int* __restrict__ cur,
                                int* __restrict__ esrc_s, int* __restrict__ eperm){
  int e = blockIdx.x*256 + threadIdx.x;
  if(e < EE){
    int d = dst[e];
    int pos = eoff[d] + atomicAdd(&cur[d], 1);
    esrc_s[pos] = src[e];
    eperm[e] = pos;
  }
}

// ---------------- generic GEMM: C[M,128] = act(A[M,K] @ W[128,K(ldw)]^T (+bias)) ----------------
template<int ACT>
__global__ __launch_bounds__(256) void k_gemm128(const float* __restrict__ A,
                                                 const float* __restrict__ W,
                                                 const float* __restrict__ bias,
                                                 float* __restrict__ C, int M, int K, int ldw){
  __shared__ float As[16][68];
  __shared__ float Bs[16][68];
  const int tid = threadIdx.x;
  const int tx = tid & 15, ty = tid >> 4;
  const int m0 = blockIdx.x * 64, c0 = blockIdx.y * 64;
  float acc[4][4] = {};
  const int lm = tid >> 2, lk = (tid & 3) * 4;

  for(int k0=0;k0<K;k0+=16){
    float4 av = make_float4(0.f,0.f,0.f,0.f);
    if(m0 + lm < M) av = *(const float4*)&A[(size_t)(m0+lm)*K + k0 + lk];
    As[lk+0][lm]=av.x; As[lk+1][lm]=av.y; As[lk+2][lm]=av.z; As[lk+3][lm]=av.w;
    float4 bv = *(const float4*)&W[(size_t)(c0+lm)*ldw + k0 + lk];
    Bs[lk+0][lm]=bv.x; Bs[lk+1][lm]=bv.y; Bs[lk+2][lm]=bv.z; Bs[lk+3][lm]=bv.w;
    __syncthreads();
#pragma unroll
    for(int k=0;k<16;k++){
      float4 a = *(const float4*)&As[k][ty*4];
      float4 b = *(const float4*)&Bs[k][tx*4];
      float aa[4] = {a.x,a.y,a.z,a.w};
      float bb[4] = {b.x,b.y,b.z,b.w};
#pragma unroll
      for(int i=0;i<4;i++)
#pragma unroll
        for(int j=0;j<4;j++) acc[i][j] += aa[i]*bb[j];
    }
    __syncthreads();
  }
#pragma unroll
  for(int i=0;i<4;i++){
    int r = m0 + ty*4 + i;
    if(r < M){
      float4 o;
      float v0=acc[i][0], v1=acc[i][1], v2=acc[i][2], v3=acc[i][3];
      int c = c0 + tx*4;
      if(ACT==1){
        v0 = leakyf(v0 + bias[c+0]); v1 = leakyf(v1 + bias[c+1]);
        v2 = leakyf(v2 + bias[c+2]); v3 = leakyf(v3 + bias[c+3]);
      }
      o.x=v0;o.y=v1;o.z=v2;o.w=v3;
      *(float4*)&C[(size_t)r*HH + c] = o;
    }
  }
}

// ---------------- GATEConv edge alpha, GEMM-free ----------------
// alpha_sorted[eperm[e]] = leaky( sum_c leaky(XP[src][c] + (ea[e]@W1e^T)[c]) * attl[c] + RD[dst[e]] )
// XP = X @ W1x^T precomputed; W1e rows held per-lane in registers.
__global__ __launch_bounds__(256) void k_gate_alpha2(const float* __restrict__ XP,
                                                     const float* __restrict__ EA,
                                                     const int* __restrict__ esrc,
                                                     const int* __restrict__ edst,
                                                     const float* __restrict__ W1,
                                                     const float* __restrict__ attl,
                                                     const float* __restrict__ RD,
                                                     const int* __restrict__ eperm,
                                                     float* __restrict__ ALPHA){
  const int lane = threadIdx.x & 63;
  const int wid = (blockIdx.x*blockDim.x + threadIdx.x) >> 6;
  const int nw  = (gridDim.x*blockDim.x) >> 6;

  float we0[16], we1[16];
#pragma unroll
  for(int f=0;f<16;f++){
    we0[f] = W1[(size_t)lane*144 + 128 + f];
    we1[f] = W1[(size_t)(lane+64)*144 + 128 + f];
  }
  const float al0 = attl[lane], al1 = attl[64+lane];

  for(int c0 = wid*64; c0 < EE; c0 += nw*64){
    const int e = c0 + lane;
    const int sIdx = esrc[e];
    const int dIdx = edst[e];
    const int pIdx = eperm[e];
    float ea[16];
    {
      const float4* g = (const float4*)&EA[(size_t)e*FE];
      float4 v0=g[0], v1=g[1], v2=g[2], v3=g[3];
      ea[0]=v0.x;ea[1]=v0.y;ea[2]=v0.z;ea[3]=v0.w;
      ea[4]=v1.x;ea[5]=v1.y;ea[6]=v1.z;ea[7]=v1.w;
      ea[8]=v2.x;ea[9]=v2.y;ea[10]=v2.z;ea[11]=v2.w;
      ea[12]=v3.x;ea[13]=v3.y;ea[14]=v3.z;ea[15]=v3.w;
    }
#pragma unroll 1
    for(int j=0;j<64;j++){
      const int sj = rdl(sIdx, j);
      float xp0 = XP[(size_t)sj*HH + lane];
      float xp1 = XP[(size_t)sj*HH + 64 + lane];
      float e0 = 0.f, e1 = 0.f;
#pragma unroll
      for(int f=0;f<16;f++){
        float wv = rdlf(ea[f], j);
        e0 += wv*we0[f]; e1 += wv*we1[f];
      }
      float p = leakyf(xp0+e0)*al0 + leakyf(xp1+e1)*al1;
      p = wsum(p);
      const int dj = rdl(dIdx, j);
      const int pj = rdl(pIdx, j);
      if(lane==0){
        ALPHA[pj] = leakyf(p + RD[dj]);
      }
    }
  }
}

// ---------------- segment softmax + weighted aggregation, one pass (online softmax) ----------------
// MODE 0: GATE (alpha precomputed & sorted), items = esrc_sorted, nseg=N
// MODE 1: ATOM (alpha = leaky(A1[items[i]] + A2[seg])), items = esrc_sorted, nseg=N
// MODE 2: MOL  (alpha = leaky(A1[i] + A2[seg])), item = i (contiguous), nseg=G
template<int MODE>
__global__ void k_agg(const int* __restrict__ off, const int* __restrict__ items,
                      const float* __restrict__ ALPHA, const float* __restrict__ A1,
                      const float* __restrict__ A2, const float* __restrict__ XSrc,
                      const float* __restrict__ bias, float* __restrict__ OUT, int nseg){
  int w = (blockIdx.x*blockDim.x + threadIdx.x) >> 6;
  int lane = threadIdx.x & 63;
  if(w >= nseg) return;
  int s0 = off[w], s1 = off[w+1];
  float a2 = (MODE==0) ? 0.f : A2[w];

  float m = -INFINITY, s = 0.f, h0 = 0.f, h1 = 0.f;

  for(int c0=s0;c0<s1;c0+=64){
    int n = min(64, s1-c0);
    int it = 0;
    float a = -INFINITY;
    if(lane < n){
      int i = c0 + lane;
      it = (MODE==2) ? i : items[i];
      if(MODE==0) a = ALPHA[i];
      else a = leakyf(A1[it] + a2);
    }
    float cm = wmax64(a);
    float mN = fmaxf(m, cm);
    float scale = (m == -INFINITY) ? 0.f : __expf(m - mN);
    float e = (lane < n) ? __expf(a - mN) : 0.f;
    s = s*scale + wsum(e);
    h0 *= scale; h1 *= scale;
    m = mN;
#pragma unroll 4
    for(int j=0;j<n;j++){
      int itj = rdl(it, j);
      float wg = rdlf(e, j);
      h0 += wg * XSrc[(size_t)itj*HH + lane];
      h1 += wg * XSrc[(size_t)itj*HH + 64 + lane];
    }
  }
  float inv = 1.f/(s + 1e-16f);
  h0 = h0*inv + bias[lane];
  h1 = h1*inv + bias[64+lane];
  OUT[(size_t)w*HH + lane]      = eluf(h0);
  OUT[(size_t)w*HH + 64 + lane] = eluf(h1);
}

// ---------------- fused GRUCell: XOUT = relu(GRU(MSG, X)) ----------------
__global__ __launch_bounds__(256) void k_gru(const float* __restrict__ MSG,
                                             const float* __restrict__ X,
                                             const float* __restrict__ Wih,
                                             const float* __restrict__ Whh,
                                             const float* __restrict__ bih,
                                             const float* __restrict__ bhh,
                                             float* __restrict__ XOUT, int M){
  __shared__ float As[2][16][68];
  __shared__ float Bs[6][16][68];
  const int tid = threadIdx.x;
  const int tx = tid & 15, ty = tid >> 4;
  const int m0 = blockIdx.x * 64, c0 = blockIdx.y * 64;
  float acc[6][4][4] = {};
  const int lm = tid >> 2, lk = (tid & 3) * 4;

  for(int k0=0;k0<HH;k0+=16){
    float4 a0 = make_float4(0,0,0,0), a1 = make_float4(0,0,0,0);
    if(m0+lm < M){
      a0 = *(const float4*)&MSG[(size_t)(m0+lm)*HH + k0 + lk];
      a1 = *(const float4*)&X  [(size_t)(m0+lm)*HH + k0 + lk];
    }
    As[0][lk+0][lm]=a0.x; As[0][lk+1][lm]=a0.y; As[0][lk+2][lm]=a0.z; As[0][lk+3][lm]=a0.w;
    As[1][lk+0][lm]=a1.x; As[1][lk+1][lm]=a1.y; As[1][lk+2][lm]=a1.z; As[1][lk+3][lm]=a1.w;
#pragma unroll
    for(int pl=0;pl<6;pl++){
      const float* Wp = (pl<3) ? Wih : Whh;
      int row = (pl%3)*HH + c0 + lm;
      float4 bv = *(const float4*)&Wp[(size_t)row*HH + k0 + lk];
      Bs[pl][lk+0][lm]=bv.x; Bs[pl][lk+1][lm]=bv.y; Bs[pl][lk+2][lm]=bv.z; Bs[pl][lk+3][lm]=bv.w;
    }
    __syncthreads();
#pragma unroll
    for(int k=0;k<16;k++){
      float4 am = *(const float4*)&As[0][k][ty*4];
      float4 ax = *(const float4*)&As[1][k][ty*4];
      float amm[4]={am.x,am.y,am.z,am.w};
      float axx[4]={ax.x,ax.y,ax.z,ax.w};
      float bb[6][4];
#pragma unroll
      for(int pl=0;pl<6;pl++){
        float4 b = *(const float4*)&Bs[pl][k][tx*4];
        bb[pl][0]=b.x; bb[pl][1]=b.y; bb[pl][2]=b.z; bb[pl][3]=b.w;
      }
#pragma unroll
      for(int i=0;i<4;i++)
#pragma unroll
        for(int j=0;j<4;j++){
          acc[0][i][j] += amm[i]*bb[0][j];
          acc[1][i][j] += amm[i]*bb[1][j];
          acc[2][i][j] += amm[i]*bb[2][j];
          acc[3][i][j] += axx[i]*bb[3][j];
          acc[4][i][j] += axx[i]*bb[4][j];
          acc[5][i][j] += axx[i]*bb[5][j];
        }
    }
    __syncthreads();
  }

  float bi0[4], bi1[4], bi2[4], bh0[4], bh1[4], bh2[4];
#pragma unroll
  for(int j=0;j<4;j++){
    int c = c0 + tx*4 + j;
    bi0[j]=bih[c]; bi1[j]=bih[c+HH]; bi2[j]=bih[c+2*HH];
    bh0[j]=bhh[c]; bh1[j]=bhh[c+HH]; bh2[j]=bhh[c+2*HH];
  }
#pragma unroll
  for(int i=0;i<4;i++){
    int r = m0 + ty*4 + i;
    if(r < M){
      float4 hp = *(const float4*)&X[(size_t)r*HH + c0 + tx*4];
      float hpv[4]={hp.x,hp.y,hp.z,hp.w};
      float ov[4];
#pragma unroll
      for(int j=0;j<4;j++){
        float ir = acc[0][i][j]+bi0[j], iz = acc[1][i][j]+bi1[j], inn = acc[2][i][j]+bi2[j];
        float hr = acc[3][i][j]+bh0[j], hz = acc[4][i][j]+bh1[j], hn  = acc[5][i][j]+bh2[j];
        float rr = sigmf(ir+hr);
        float z  = sigmf(iz+hz);
        float ng = tanh_fast(inn + rr*hn);
        float nx = (1.f - z)*ng + z*hpv[j];
        ov[j] = fmaxf(nx, 0.f);
      }
      float4 o; o.x=ov[0]; o.y=ov[1]; o.z=ov[2]; o.w=ov[3];
      *(float4*)&XOUT[(size_t)r*HH + c0 + tx*4] = o;
    }
  }
}

// ---------------- small per-row kernels ----------------
__global__ void k_dot2(const float* __restrict__ X, const float* __restrict__ u,
                       const float* __restrict__ v, float* __restrict__ a,
                       float* __restrict__ b, int M){
  int w = (blockIdx.x*blockDim.x + threadIdx.x) >> 6;
  int lane = threadIdx.x & 63;
  if(w >= M) return;
  float x0 = X[(size_t)w*HH + lane];
  float x1 = X[(size_t)w*HH + 64 + lane];
  float p = x0*u[lane] + x1*u[64+lane];
  p = wsum(p);
  if(lane==0) a[w] = p;
  if(v){
    float q = x0*v[lane] + x1*v[64+lane];
    q = wsum(q);
    if(lane==0) b[w] = q;
  }
}

__global__ void k_ginit(const int* __restrict__ goff, const float* __restrict__ X,
                        float* __restrict__ OUT){
  int g = (blockIdx.x*blockDim.x + threadIdx.x) >> 6;
  int lane = threadIdx.x & 63;
  if(g >= GG) return;
  int s0 = goff[g], s1 = goff[g+1];
  float h0=0.f, h1=0.f;
  for(int n=s0;n<s1;n++){
    h0 += X[(size_t)n*HH + lane];
    h1 += X[(size_t)n*HH + 64 + lane];
  }
  OUT[(size_t)g*HH + lane]      = fmaxf(h0, 0.f);
  OUT[(size_t)g*HH + 64 + lane] = fmaxf(h1, 0.f);
}

__global__ void k_weff(const float* __restrict__ lin2W, const float* __restrict__ lin2b,
                       const float* __restrict__ finW, const float* __restrict__ finb,
                       float* __restrict__ weff){
  int c = threadIdx.x;
  float s = 0.f;
  for(int j=0;j<HH;j++) s += finW[j]*lin2W[(size_t)j*HH + c];
  weff[c] = s;
  if(c==0){
    float bb = finb[0];
    for(int j=0;j<HH;j++) bb += lin2b[j]*finW[j];
    weff[HH] = bb;
  }
}

__global__ void k_final(const float* __restrict__ OUT, const float* __restrict__ weff,
                        float* __restrict__ y){
  int g = (blockIdx.x*blockDim.x + threadIdx.x) >> 6;
  int lane = threadIdx.x & 63;
  if(g >= GG) return;
  float p = OUT[(size_t)g*HH + lane]*weff[lane] + OUT[(size_t)g*HH + 64 + lane]*weff[64+lane];
  p = wsum(p);
  if(lane==0) y[g] = sigmf(p + weff[HH]);
}

// ---------------- host ----------------
extern "C" void kernel_launch(void* const* d_in, const int* in_sizes, int n_in,
                              void* d_out, int out_size, void* d_ws, size_t ws_size,
                              hipStream_t stream){
  const float* in_x   = (const float*)d_in[0];
  const int*   eidx   = (const int*)d_in[1];
  const float* ea     = (const float*)d_in[2];
  const int*   batch  = (const int*)d_in[3];
  const float* lin1W  = (const float*)d_in[4];
  const float* lin1b  = (const float*)d_in[5];
  const float* gattl  = (const float*)d_in[6];
  const float* gattr  = (const float*)d_in[7];
  const float* glin1W = (const float*)d_in[8];
  const float* glin2W = (const float*)d_in[9];
  const float* gbias  = (const float*)d_in[10];
  const float* g0Wih  = (const float*)d_in[11];
  const float* g0Whh  = (const float*)d_in[12];
  const float* g0bih  = (const float*)d_in[13];
  const float* g0bhh  = (const float*)d_in[14];
  const float* aLinW  = (const float*)d_in[15];
  const float* aAttS  = (const float*)d_in[16];
  const float* aAttD  = (const float*)d_in[17];
  const float* aBias  = (const float*)d_in[18];
  const float* aGWih  = (const float*)d_in[19];
  const float* aGWhh  = (const float*)d_in[20];
  const float* aGbih  = (const float*)d_in[21];
  const float* aGbhh  = (const float*)d_in[22];
  const float* mLinW  = (const float*)d_in[23];
  const float* mAttS  = (const float*)d_in[24];
  const float* mAttD  = (const float*)d_in[25];
  const float* mBias  = (const float*)d_in[26];
  const float* mGWih  = (const float*)d_in[27];
  const float* mGWhh  = (const float*)d_in[28];
  const float* mGbih  = (const float*)d_in[29];
  const float* mGbhh  = (const float*)d_in[30];
  const float* lin2W  = (const float*)d_in[31];
  const float* lin2b  = (const float*)d_in[32];
  const float* finW   = (const float*)d_in[33];
  const float* finb   = (const float*)d_in[34];

  const int* esrc0 = eidx;
  const int* edst0 = eidx + EE;

  char* w = (char*)d_ws;
  size_t o = 0;
  auto alloc = [&](size_t bytes)->void*{
    void* p = w + o;
    o = (o + bytes + 255) & ~(size_t)255;
    return p;
  };
  float* X    = (float*)alloc((size_t)NN*HH*4);
  float* XB   = (float*)alloc((size_t)NN*HH*4);
  float* XS   = (float*)alloc((size_t)NN*HH*4);
  float* MSG  = (float*)alloc((size_t)NN*HH*4);
  float* XP   = (float*)alloc((size_t)NN*HH*4);
  float* ALPHA= (float*)alloc((size_t)EE*4);
  float* S1   = (float*)alloc((size_t)NN*4);
  float* S2   = (float*)alloc((size_t)NN*4);
  float* ADSTG= (float*)alloc((size_t)GG*4);
  float* OUTg = (float*)alloc((size_t)GG*HH*4);
  float* OUTb = (float*)alloc((size_t)GG*HH*4);
  float* HG   = (float*)alloc((size_t)GG*HH*4);
  float* ODg  = (float*)alloc((size_t)GG*HH*4);
  float* WEFF = (float*)alloc(256*4);
  int* zeroreg= (int*)alloc((size_t)(NN + NN + 2048)*4);
  int* deg  = zeroreg;
  int* cur  = zeroreg + NN;
  int* gcnt = zeroreg + 2*NN;
  int* eoff = (int*)alloc((size_t)(NN+1)*4);
  int* goff = (int*)alloc((size_t)(GG+1)*4);
  int* esrcS= (int*)alloc((size_t)EE*4);
  int* eperm= (int*)alloc((size_t)EE*4);

  // ---- CSR build ----
  hipMemsetAsync(zeroreg, 0, (size_t)(NN + NN + 2048)*4, stream);
  k_count_edges<<<EE/256, 256, 0, stream>>>(edst0, deg);
  k_scan<<<1, 1024, 0, stream>>>(deg, eoff, NN);
  k_scatter_edges<<<EE/256, 256, 0, stream>>>(esrc0, edst0, eoff, cur, esrcS, eperm);
  k_count_graphs<<<(NN+255)/256, 256, 0, stream>>>(batch, gcnt);
  k_scan<<<1, 1024, 0, stream>>>(gcnt, goff, GG);

  const int gN  = (NN + 63)/64;
  const int gG  = (GG + 63)/64;
  dim3 gemmN(gN, 2), gemmG(gG, 2);

  // ---- input projection ----
  k_gemm128<1><<<gemmN, 256, 0, stream>>>(in_x, lin1W, lin1b, X, NN, FN, FN);

  // ---- GATEConv ----
  k_dot2<<<(NN+3)/4, 256, 0, stream>>>(X, gattr, nullptr, S1, nullptr, NN);        // RD per node
  k_gemm128<0><<<gemmN, 256, 0, stream>>>(X, glin1W, nullptr, XP, NN, HH, 144);    // XP = X @ W1x^T
  k_gemm128<0><<<gemmN, 256, 0, stream>>>(X, glin2W, nullptr, XS, NN, HH, HH);
  k_gate_alpha2<<<1024, 256, 0, stream>>>(XP, ea, esrc0, edst0, glin1W, gattl, S1, eperm, ALPHA);
  k_agg<0><<<(NN+3)/4, 256, 0, stream>>>(eoff, esrcS, ALPHA, nullptr, nullptr, XS, gbias, MSG, NN);
  k_gru<<<gemmN, 256, 0, stream>>>(MSG, X, g0Wih, g0Whh, g0bih, g0bhh, XB, NN);
  { float* t = X; X = XB; XB = t; }

  // ---- atom GATConv layers ----
  for(int l=0;l<2;l++){
    const float* Wl   = aLinW + (size_t)l*HH*HH;
    const float* asl  = aAttS + (size_t)l*HH;
    const float* adl  = aAttD + (size_t)l*HH;
    const float* bl   = aBias + (size_t)l*HH;
    const float* wih  = aGWih + (size_t)l*3*HH*HH;
    const float* whh  = aGWhh + (size_t)l*3*HH*HH;
    const float* bi   = aGbih + (size_t)l*3*HH;
    const float* bh   = aGbhh + (size_t)l*3*HH;
    k_gemm128<0><<<gemmN, 256, 0, stream>>>(X, Wl, nullptr, XS, NN, HH, HH);
    k_dot2<<<(NN+3)/4, 256, 0, stream>>>(XS, asl, adl, S1, S2, NN);
    k_agg<1><<<(NN+3)/4, 256, 0, stream>>>(eoff, esrcS, nullptr, S1, S2, XS, bl, MSG, NN);
    k_gru<<<gemmN, 256, 0, stream>>>(MSG, X, wih, whh, bi, bh, XB, NN);
    { float* t = X; X = XB; XB = t; }
  }

  // ---- molecule readout ----
  k_ginit<<<(GG+3)/4, 256, 0, stream>>>(goff, X, OUTg);
  k_gemm128<0><<<gemmN, 256, 0, stream>>>(X, mLinW, nullptr, XS, NN, HH, HH);
  k_dot2<<<(NN+3)/4, 256, 0, stream>>>(XS, mAttS, nullptr, S1, nullptr, NN);

  float* Ocur = OUTg;
  float* Onxt = OUTb;
  for(int t=0;t<3;t++){
    k_gemm128<0><<<gemmG, 256, 0, stream>>>(Ocur, mLinW, nullptr, ODg, GG, HH, HH);
    k_dot2<<<(GG+3)/4, 256, 0, stream>>>(ODg, mAttD, nullptr, ADSTG, nullptr, GG);
    k_agg<2><<<(GG+3)/4, 256, 0, stream>>>(goff, nullptr, nullptr, S1, ADSTG, XS, mBias, HG, GG);
    k_gru<<<gemmG, 256, 0, stream>>>(HG, Ocur, mGWih, mGWhh, mGbih, mGbhh, Onxt, GG);
    { float* tt = Ocur; Ocur = Onxt; Onxt = tt; }
  }

  // ---- fused lin2 + final ----
  k_weff<<<1, 128, 0, stream>>>(lin2W, lin2b, finW, finb, WEFF);
  k_final<<<(GG+3)/4, 256, 0, stream>>>(Ocur, WEFF, (float*)d_out);
}